// Round 6
// baseline (512.855 us; speedup 1.0000x reference)
//
#include <hip/hip_runtime.h>

#define N_TOK 4096
#define DIM   1024
#define NE    16
#define NF    512
#define TOPK  4
#define CAP   4096
#define NPAIR (N_TOK * TOPK)
#define MAXTILES 144   // sum ceil(cnt/128) <= 128 + 16

typedef _Float16 v8h __attribute__((ext_vector_type(8)));
typedef float    v4f __attribute__((ext_vector_type(4)));

// ---------------------------------------------------------------- router ----
// one wave/token: fp64 logits -> top-4 -> renormalized weights; ALSO casts the
// (L1-hot) x row to f16 xb, replacing the separate cast_x launch.
__global__ __launch_bounds__(64) void router_kernel(
    const float* __restrict__ x, const float* __restrict__ Wr,
    int* __restrict__ tokIdx, float* __restrict__ tokW,
    unsigned short* __restrict__ xb)
{
    int t = blockIdx.x;
    int l = threadIdx.x;
    double z[NE];
#pragma unroll
    for (int e = 0; e < NE; e++) z[e] = 0.0;
    const float* xrow = x + (size_t)t * DIM;
#pragma unroll
    for (int i = 0; i < 16; i++) {
        int d = i * 64 + l;
        double xv = (double)xrow[d];
        const float4* wr = (const float4*)(Wr + d * NE);
        float4 w0 = wr[0], w1 = wr[1], w2 = wr[2], w3 = wr[3];
        z[0]  += xv * w0.x; z[1]  += xv * w0.y; z[2]  += xv * w0.z; z[3]  += xv * w0.w;
        z[4]  += xv * w1.x; z[5]  += xv * w1.y; z[6]  += xv * w1.z; z[7]  += xv * w1.w;
        z[8]  += xv * w2.x; z[9]  += xv * w2.y; z[10] += xv * w2.z; z[11] += xv * w2.w;
        z[12] += xv * w3.x; z[13] += xv * w3.y; z[14] += xv * w3.z; z[15] += xv * w3.w;
    }
    // fused cast: two 8-elem chunks per lane (row is L1-hot)
    const float4* xv4 = (const float4*)xrow;
#pragma unroll
    for (int h2 = 0; h2 < 2; h2++) {
        int base = h2 * 512 + l * 8;
        float4 a = xv4[h2 * 128 + l * 2];
        float4 b = xv4[h2 * 128 + l * 2 + 1];
        union { unsigned short u[8]; uint4 v; } p;
        p.u[0] = __builtin_bit_cast(unsigned short, (_Float16)a.x);
        p.u[1] = __builtin_bit_cast(unsigned short, (_Float16)a.y);
        p.u[2] = __builtin_bit_cast(unsigned short, (_Float16)a.z);
        p.u[3] = __builtin_bit_cast(unsigned short, (_Float16)a.w);
        p.u[4] = __builtin_bit_cast(unsigned short, (_Float16)b.x);
        p.u[5] = __builtin_bit_cast(unsigned short, (_Float16)b.y);
        p.u[6] = __builtin_bit_cast(unsigned short, (_Float16)b.z);
        p.u[7] = __builtin_bit_cast(unsigned short, (_Float16)b.w);
        *(uint4*)(xb + (size_t)t * DIM + base) = p.v;
    }
#pragma unroll
    for (int e = 0; e < NE; e++) {
#pragma unroll
        for (int m = 1; m < 64; m <<= 1) z[e] += __shfl_xor(z[e], m, 64);
    }
    if (l == 0) {
        bool taken[NE];
#pragma unroll
        for (int e = 0; e < NE; e++) taken[e] = false;
        int idx[TOPK]; double sel[TOPK];
        for (int k = 0; k < TOPK; k++) {
            int bi = 0; double bv = -1.0e300;
            for (int e = 0; e < NE; e++)
                if (!taken[e] && z[e] > bv) { bv = z[e]; bi = e; }
            taken[bi] = true; idx[k] = bi; sel[k] = bv;
        }
        double m = sel[0];
        double ex[TOPK]; double s = 0.0;
        for (int k = 0; k < TOPK; k++) { ex[k] = exp(sel[k] - m); s += ex[k]; }
        for (int k = 0; k < TOPK; k++) {
            tokIdx[t * TOPK + k] = idx[k];
            tokW[t * TOPK + k]   = (float)(ex[k] / s);
        }
    }
}

// ------------------------------------------------------------------ binning --
__global__ __launch_bounds__(1024) void bin_kernel(
    const int* __restrict__ tokIdx,
    int* __restrict__ cnt, int* __restrict__ ptile,
    int* __restrict__ tileE, int* __restrict__ tileMt,
    int* __restrict__ bpair)
{
    int wv = threadIdx.x >> 6;
    int lane = threadIdx.x & 63;
    __shared__ int scnt[NE];

    int c = 0;
    for (int i0 = lane * 4; i0 < NPAIR; i0 += 256) {
        int4 v = *(const int4*)(tokIdx + i0);
        c += (v.x == wv) + (v.y == wv) + (v.z == wv) + (v.w == wv);
    }
#pragma unroll
    for (int m = 1; m < 64; m <<= 1) c += __shfl_xor(c, m, 64);
    if (lane == 0) scnt[wv] = c;
    __syncthreads();
    if (threadIdx.x == 0) {
        int rt = 0;
        for (int e = 0; e < NE; e++) {
            cnt[e] = scnt[e];
            ptile[e] = rt;
            int nt = (scnt[e] + 127) >> 7;
            for (int t = 0; t < nt; t++) { tileE[rt + t] = e; tileMt[rt + t] = t; }
            rt += nt;
        }
        for (; rt < MAXTILES; rt++) tileE[rt] = -1;
    }

    int pos = 0;
    for (int i0b = 0; i0b < NPAIR; i0b += 256) {
        int i0 = i0b + lane * 4;
        int4 v = *(const int4*)(tokIdx + i0);
        int ev[4] = {v.x, v.y, v.z, v.w};
#pragma unroll
        for (int j = 0; j < 4; j++) {
            bool m = (ev[j] == wv);
            unsigned long long bal = __ballot(m);
            if (m) {
                int r = __popcll(bal & ((1ULL << lane) - 1ULL));
                bpair[wv * CAP + pos + r] = i0 + j;
            }
            pos += __popcll(bal);
        }
    }
}

// ----------------------------------------------------------- weight prep ----
// one launch for Wg+Wu+Wd: [E][R][C] f32 -> B^T tiled f16 images
// out[e][cb][kt][RI][32]; z = which*16 + e.
__global__ __launch_bounds__(256) void prep_weight_kernel(
    const float* __restrict__ Wg, const float* __restrict__ Wu,
    const float* __restrict__ Wd,
    unsigned short* __restrict__ Wg_t, unsigned short* __restrict__ Wu_t,
    unsigned short* __restrict__ Wd_t)
{
    int z = blockIdx.y;
    int which = z >> 4, e = z & 15;
    const float* src; unsigned short* dst; int R, C, RIL;
    if (which == 0)      { src = Wg; dst = Wg_t; R = DIM; C = NF;  RIL = 6; }
    else if (which == 1) { src = Wu; dst = Wu_t; R = DIM; C = NF;  RIL = 6; }
    else                 { src = Wd; dst = Wd_t; R = NF;  C = DIM; RIL = 7; }
    int bx = blockIdx.x;  // 128 blocks cover (R/64)*(C/64)
    int cbl, rbl;
    if (which < 2) { cbl = bx & 7;  rbl = bx >> 3; }
    else           { cbl = bx & 15; rbl = bx >> 4; }
    int c0 = cbl * 64, r0 = rbl * 64;

    __shared__ float tile[64][65];
    const float* s = src + (size_t)e * R * C;
    int t = threadIdx.x;
    int tr = t >> 4, tc = (t & 15) * 4;
#pragma unroll
    for (int i = 0; i < 4; i++) {
        int row = i * 16 + tr;
        float4 v = *(const float4*)(s + (size_t)(r0 + row) * C + c0 + tc);
        tile[row][tc + 0] = v.x; tile[row][tc + 1] = v.y;
        tile[row][tc + 2] = v.z; tile[row][tc + 3] = v.w;
    }
    __syncthreads();
    int ktPerE = R >> 5;
    int cbPerE = C >> RIL;
    int imgSz  = (1 << RIL) * 32;
#pragma unroll
    for (int i = 0; i < 4; i++) {
        int nr = i * 16 + tr;
        int orow = c0 + nr;
        int k0 = r0 + tc;
        int cb = orow >> RIL;
        int r  = orow & ((1 << RIL) - 1);
        int kt = k0 >> 5;
        size_t off = ((size_t)(e * cbPerE + cb) * ktPerE + kt) * imgSz
                   + r * 32 + (k0 & 31);
        union { unsigned short u[4]; uint2 v; } p;
#pragma unroll
        for (int j = 0; j < 4; j++)
            p.u[j] = __builtin_bit_cast(unsigned short, (_Float16)tile[tc + j][nr]);
        *(uint2*)(dst + off) = p.v;
    }
}

// LDS swizzle for 64-wide k rows (8 chunks of 16B): 8-cycle-min b128 access
__device__ __forceinline__ int ldsw64(int row, int chunk) {
    return row * 64 + (chunk ^ (row & 7)) * 8;
}

// --------------------------------------------------------- gate/up + silu ----
// 128 slots x 64 f-cols; BK=64 (32 MFMA per barrier pair); prefetch issued
// INSIDE the MFMA phase so the vmcnt drain at the next barrier is covered.
__global__ __launch_bounds__(256) void ffn_gate_up_kernel(
    const unsigned short* __restrict__ xb,
    const unsigned short* __restrict__ Wg_t,   // [e][fb8][kt32][64][32]
    const unsigned short* __restrict__ Wu_t,
    const int* __restrict__ cnt, const int* __restrict__ ptile,
    const int* __restrict__ tileE, const int* __restrict__ tileMt,
    const int* __restrict__ bpair,
    unsigned short* __restrict__ h_t)          // [tile][kt16][128][32]
{
    int fb = blockIdx.x, ti = blockIdx.y;
    int e = tileE[ti];
    if (e < 0) return;
    int mt = tileMt[ti];
    int count = cnt[e];

    __shared__ __align__(16) unsigned short sX[128 * 64];
    __shared__ __align__(16) unsigned short sG[64 * 64];
    __shared__ __align__(16) unsigned short sU[64 * 64];
    __shared__ int sTok[128];

    int tid = threadIdx.x, lane = tid & 63, w = tid >> 6;
    if (tid < 128) {
        int pos = mt * 128 + tid;
        sTok[tid] = bpair[e * CAP + min(pos, count - 1)] >> 2;
    }
    __syncthreads();

    // X staging: row xr = tid>>1, logical chunks (tid&1)*4+j (64B contiguous)
    int xr = tid >> 1, xcb = (tid & 1) * 4;
    const unsigned short* xsrc = xb + (size_t)sTok[xr] * DIM + xcb * 8;
    unsigned short* xdst[4];
#pragma unroll
    for (int j = 0; j < 4; j++) xdst[j] = &sX[ldsw64(xr, xcb + j)];

    // weight staging: g = 2*tid+j over 512 chunks (2 images of 4KB)
    const unsigned short* gW = Wg_t + (size_t)(e * 8 + fb) * 65536 + (size_t)(2 * tid) * 8;
    const unsigned short* gU = Wu_t + (size_t)(e * 8 + fb) * 65536 + (size_t)(2 * tid) * 8;
    int wrr = (tid >> 1) & 63;
    unsigned short* gdst[2]; unsigned short* udst[2];
#pragma unroll
    for (int j = 0; j < 2; j++) {
        int g = 2 * tid + j;
        int c = (g >> 8) * 4 + (g & 3);
        gdst[j] = &sG[ldsw64(wrr, c)];
        udst[j] = &sU[ldsw64(wrr, c)];
    }

    int row = lane & 15, q = lane >> 4;
    int rw = w & 1, cw = w >> 1;
    int aoff[2][4], goff[2][2];
#pragma unroll
    for (int kk = 0; kk < 2; kk++) {
#pragma unroll
        for (int mi = 0; mi < 4; mi++)
            aoff[kk][mi] = ldsw64(rw * 64 + mi * 16 + row, kk * 4 + q);
#pragma unroll
        for (int ni = 0; ni < 2; ni++)
            goff[kk][ni] = ldsw64(cw * 32 + ni * 16 + row, kk * 4 + q);
    }

    v4f accG[4][2], accU[4][2];
    v4f zero = {0.f, 0.f, 0.f, 0.f};
#pragma unroll
    for (int mi = 0; mi < 4; mi++)
#pragma unroll
        for (int ni = 0; ni < 2; ni++) { accG[mi][ni] = zero; accU[mi][ni] = zero; }

    uint4 px[4], pg[2], pu[2];
#pragma unroll
    for (int j = 0; j < 4; j++) px[j] = *(const uint4*)(xsrc + j * 8);
#pragma unroll
    for (int j = 0; j < 2; j++) {
        pg[j] = *(const uint4*)(gW + j * 8);
        pu[j] = *(const uint4*)(gU + j * 8);
    }

#pragma unroll 1
    for (int s = 0; s < 16; s++) {
        __syncthreads();     // prev reads done; drains loads issued during prev MFMA phase
#pragma unroll
        for (int j = 0; j < 4; j++) *(uint4*)xdst[j] = px[j];
#pragma unroll
        for (int j = 0; j < 2; j++) { *(uint4*)gdst[j] = pg[j]; *(uint4*)udst[j] = pu[j]; }
        __syncthreads();
        v8h a[4], bg[2], bu[2];
#pragma unroll
        for (int mi = 0; mi < 4; mi++) a[mi] = *(const v8h*)&sX[aoff[0][mi]];
#pragma unroll
        for (int ni = 0; ni < 2; ni++) {
            bg[ni] = *(const v8h*)&sG[goff[0][ni]];
            bu[ni] = *(const v8h*)&sU[goff[0][ni]];
        }
        if (s < 15) {        // prefetch flies over the 32-MFMA phase
#pragma unroll
            for (int j = 0; j < 4; j++)
                px[j] = *(const uint4*)(xsrc + (s + 1) * 64 + j * 8);
#pragma unroll
            for (int j = 0; j < 2; j++) {
                pg[j] = *(const uint4*)(gW + (size_t)(s + 1) * 4096 + j * 8);
                pu[j] = *(const uint4*)(gU + (size_t)(s + 1) * 4096 + j * 8);
            }
        }
#pragma unroll
        for (int mi = 0; mi < 4; mi++)
#pragma unroll
            for (int ni = 0; ni < 2; ni++) {
                accG[mi][ni] = __builtin_amdgcn_mfma_f32_16x16x32_f16(a[mi], bg[ni], accG[mi][ni], 0, 0, 0);
                accU[mi][ni] = __builtin_amdgcn_mfma_f32_16x16x32_f16(a[mi], bu[ni], accU[mi][ni], 0, 0, 0);
            }
#pragma unroll
        for (int mi = 0; mi < 4; mi++) a[mi] = *(const v8h*)&sX[aoff[1][mi]];
#pragma unroll
        for (int ni = 0; ni < 2; ni++) {
            bg[ni] = *(const v8h*)&sG[goff[1][ni]];
            bu[ni] = *(const v8h*)&sU[goff[1][ni]];
        }
#pragma unroll
        for (int mi = 0; mi < 4; mi++)
#pragma unroll
            for (int ni = 0; ni < 2; ni++) {
                accG[mi][ni] = __builtin_amdgcn_mfma_f32_16x16x32_f16(a[mi], bg[ni], accG[mi][ni], 0, 0, 0);
                accU[mi][ni] = __builtin_amdgcn_mfma_f32_16x16x32_f16(a[mi], bu[ni], accU[mi][ni], 0, 0, 0);
            }
    }

    size_t himg = (size_t)(ptile[e] + mt) * 16;
#pragma unroll
    for (int mi = 0; mi < 4; mi++)
#pragma unroll
        for (int ni = 0; ni < 2; ni++) {
            int f = fb * 64 + cw * 32 + ni * 16 + row;    // C/D: col = lane&15
#pragma unroll
            for (int i = 0; i < 4; i++) {
                int rl = rw * 64 + mi * 16 + q * 4 + i;   // C/D: row = quad*4+reg
                int pos = mt * 128 + rl;
                if (pos < count) {
                    float gv = accG[mi][ni][i];
                    float uv = accU[mi][ni][i];
                    float hv = gv * uv / (1.0f + __expf(-gv));
                    size_t off = (himg + (f >> 5)) * 4096 + rl * 32 + (f & 31);
                    h_t[off] = __builtin_bit_cast(unsigned short, (_Float16)hv);
                }
            }
        }
}

// ----------------------------------------------------------- down (no atomics)
__global__ __launch_bounds__(256) void ffn_down_kernel(
    const unsigned short* __restrict__ h_t,
    const unsigned short* __restrict__ Wd_t,   // [e][db8][kt16][128][32]
    const int* __restrict__ cnt, const int* __restrict__ ptile,
    const int* __restrict__ tileE, const int* __restrict__ tileMt,
    const int* __restrict__ bpair,
    unsigned short* __restrict__ part)         // [NPAIR][DIM] f16
{
    int ti = blockIdx.x, db = blockIdx.y;
    int e = tileE[ti];
    if (e < 0) return;
    int mt = tileMt[ti];
    int count = cnt[e];

    __shared__ __align__(16) unsigned short sH[128 * 64];
    __shared__ __align__(16) unsigned short sW[128 * 64];
    __shared__ int sPair[128];

    int tid = threadIdx.x, lane = tid & 63, w = tid >> 6;
    if (tid < 128) {
        int pos = mt * 128 + tid;
        sPair[tid] = bpair[e * CAP + min(pos, count - 1)];
    }
    __syncthreads();

    // staging: j=0..3, g = j*256+tid; i=g>>9, r=(g>>2)&127, c4=tid&3
    const unsigned short* hsrc = h_t + (size_t)(ptile[e] + mt) * 65536 + (size_t)tid * 8;
    const unsigned short* wsrc = Wd_t + (size_t)(e * 8 + db) * 65536 + (size_t)tid * 8;
    unsigned short* hdst[4]; unsigned short* wdst[4];
#pragma unroll
    for (int j = 0; j < 4; j++) {
        int g = j * 256 + tid;
        int r = (g >> 2) & 127;
        int c = (g >> 9) * 4 + (tid & 3);
        hdst[j] = &sH[ldsw64(r, c)];
        wdst[j] = &sW[ldsw64(r, c)];
    }

    int row = lane & 15, q = lane >> 4;
    int rw = w & 1, cw = w >> 1;
    int aoff[2][4], boff[2][4];
#pragma unroll
    for (int kk = 0; kk < 2; kk++) {
#pragma unroll
        for (int mi = 0; mi < 4; mi++)
            aoff[kk][mi] = ldsw64(rw * 64 + mi * 16 + row, kk * 4 + q);
#pragma unroll
        for (int ni = 0; ni < 4; ni++)
            boff[kk][ni] = ldsw64(cw * 64 + ni * 16 + row, kk * 4 + q);
    }

    v4f acc[4][4];
    v4f zero = {0.f, 0.f, 0.f, 0.f};
#pragma unroll
    for (int mi = 0; mi < 4; mi++)
#pragma unroll
        for (int ni = 0; ni < 4; ni++) acc[mi][ni] = zero;

    uint4 ph[4], pw[4];
#pragma unroll
    for (int j = 0; j < 4; j++) {
        ph[j] = *(const uint4*)(hsrc + (size_t)j * 2048);
        pw[j] = *(const uint4*)(wsrc + (size_t)j * 2048);
    }

#pragma unroll 1
    for (int s = 0; s < 8; s++) {
        __syncthreads();
#pragma unroll
        for (int j = 0; j < 4; j++) { *(uint4*)hdst[j] = ph[j]; *(uint4*)wdst[j] = pw[j]; }
        __syncthreads();
        v8h a[4], b[4];
#pragma unroll
        for (int mi = 0; mi < 4; mi++) a[mi] = *(const v8h*)&sH[aoff[0][mi]];
#pragma unroll
        for (int ni = 0; ni < 4; ni++) b[ni] = *(const v8h*)&sW[boff[0][ni]];
        if (s < 7) {
#pragma unroll
            for (int j = 0; j < 4; j++) {
                ph[j] = *(const uint4*)(hsrc + (size_t)(s + 1) * 8192 + (size_t)j * 2048);
                pw[j] = *(const uint4*)(wsrc + (size_t)(s + 1) * 8192 + (size_t)j * 2048);
            }
        }
#pragma unroll
        for (int mi = 0; mi < 4; mi++)
#pragma unroll
            for (int ni = 0; ni < 4; ni++)
                acc[mi][ni] = __builtin_amdgcn_mfma_f32_16x16x32_f16(a[mi], b[ni], acc[mi][ni], 0, 0, 0);
#pragma unroll
        for (int mi = 0; mi < 4; mi++) a[mi] = *(const v8h*)&sH[aoff[1][mi]];
#pragma unroll
        for (int ni = 0; ni < 4; ni++) b[ni] = *(const v8h*)&sW[boff[1][ni]];
#pragma unroll
        for (int mi = 0; mi < 4; mi++)
#pragma unroll
            for (int ni = 0; ni < 4; ni++)
                acc[mi][ni] = __builtin_amdgcn_mfma_f32_16x16x32_f16(a[mi], b[ni], acc[mi][ni], 0, 0, 0);
    }

#pragma unroll
    for (int mi = 0; mi < 4; mi++)
#pragma unroll
        for (int ni = 0; ni < 4; ni++) {
            int col = db * 128 + cw * 64 + ni * 16 + row;
#pragma unroll
            for (int i = 0; i < 4; i++) {
                int rl = rw * 64 + mi * 16 + q * 4 + i;
                int pos = mt * 128 + rl;
                if (pos < count) {
                    int p = sPair[rl];
                    part[(size_t)p * DIM + col] =
                        __builtin_bit_cast(unsigned short, (_Float16)acc[mi][ni][i]);
                }
            }
        }
}

// ---------------------------------------------------------------- combine ----
__global__ __launch_bounds__(256) void combine_kernel(
    const unsigned short* __restrict__ part, const float* __restrict__ tokW,
    float* __restrict__ out)
{
    int gid = blockIdx.x * 256 + threadIdx.x;
    int t = gid >> 8;
    int c = (gid & 255) * 4;
    float4 r = {0.f, 0.f, 0.f, 0.f};
#pragma unroll
    for (int k = 0; k < TOPK; k++) {
        float wk = tokW[t * TOPK + k];
        union { uint2 u; _Float16 h[4]; } cv;
        cv.u = *(const uint2*)(part + ((size_t)(t * TOPK + k)) * DIM + c);
        r.x += wk * (float)cv.h[0];
        r.y += wk * (float)cv.h[1];
        r.z += wk * (float)cv.h[2];
        r.w += wk * (float)cv.h[3];
    }
    *(float4*)(out + (size_t)t * DIM + c) = r;
}

// ------------------------------------------------------------------- host ----
extern "C" void kernel_launch(void* const* d_in, const int* in_sizes, int n_in,
                              void* d_out, int out_size, void* d_ws, size_t ws_size,
                              hipStream_t stream)
{
    const float* x  = (const float*)d_in[0];
    const float* Wr = (const float*)d_in[1];
    const float* Wg = (const float*)d_in[2];
    const float* Wu = (const float*)d_in[3];
    const float* Wd = (const float*)d_in[4];
    float* out = (float*)d_out;
    char* ws = (char*)d_ws;

    size_t off = 0;
    int* tokIdx = (int*)(ws + off);   off += (size_t)NPAIR * 4;
    float* tokW = (float*)(ws + off); off += (size_t)NPAIR * 4;
    int* cnt    = (int*)(ws + off);   off += 256;
    int* ptile  = (int*)(ws + off);   off += 256;
    int* tileE  = (int*)(ws + off);   off += MAXTILES * 4;
    int* tileMt = (int*)(ws + off);   off += MAXTILES * 4;
    int* bpair  = (int*)(ws + off);   off += (size_t)NE * CAP * 4;
    unsigned short* xb   = (unsigned short*)(ws + off); off += (size_t)N_TOK * DIM * 2;
    unsigned short* Wg_t = (unsigned short*)(ws + off); off += (size_t)NE * DIM * NF * 2;
    unsigned short* Wu_t = (unsigned short*)(ws + off); off += (size_t)NE * DIM * NF * 2;
    unsigned short* Wd_t = (unsigned short*)(ws + off); off += (size_t)NE * DIM * NF * 2;
    unsigned short* h_t  = (unsigned short*)(ws + off); off += (size_t)MAXTILES * 16 * 4096 * 2;
    unsigned short* part = (unsigned short*)(ws + off); off += (size_t)NPAIR * DIM * 2;

    router_kernel<<<N_TOK, 64, 0, stream>>>(x, Wr, tokIdx, tokW, xb);
    bin_kernel<<<1, 1024, 0, stream>>>(tokIdx, cnt, ptile, tileE, tileMt, bpair);
    prep_weight_kernel<<<dim3(128, 48), 256, 0, stream>>>(Wg, Wu, Wd, Wg_t, Wu_t, Wd_t);
    ffn_gate_up_kernel<<<dim3(8, MAXTILES), 256, 0, stream>>>(
        xb, Wg_t, Wu_t, cnt, ptile, tileE, tileMt, bpair, h_t);
    ffn_down_kernel<<<dim3(MAXTILES, 8), 256, 0, stream>>>(
        h_t, Wd_t, cnt, ptile, tileE, tileMt, bpair, part);
    combine_kernel<<<(N_TOK * DIM) / (256 * 4), 256, 0, stream>>>(part, tokW, out);
}

// Round 7
// 288.727 us; speedup vs baseline: 1.7763x; 1.7763x over previous
//
#include <hip/hip_runtime.h>

#define N_TOK 4096
#define DIM   1024
#define NE    16
#define NF    512
#define TOPK  4
#define CAP   4096
#define NPAIR (N_TOK * TOPK)
#define MAXTILES 144   // sum ceil(cnt/128) <= 128 + 16

typedef _Float16 v8h __attribute__((ext_vector_type(8)));
typedef float    v4f __attribute__((ext_vector_type(4)));

// ---------------------------------------------------------------- router ----
// one wave/token: fp64 logits -> top-4 -> renormalized weights; also casts the
// (L1-hot) x row to f16 xb (replaces a separate cast launch).
__global__ __launch_bounds__(64) void router_kernel(
    const float* __restrict__ x, const float* __restrict__ Wr,
    int* __restrict__ tokIdx, float* __restrict__ tokW,
    unsigned short* __restrict__ xb)
{
    int t = blockIdx.x;
    int l = threadIdx.x;
    double z[NE];
#pragma unroll
    for (int e = 0; e < NE; e++) z[e] = 0.0;
    const float* xrow = x + (size_t)t * DIM;
#pragma unroll
    for (int i = 0; i < 16; i++) {
        int d = i * 64 + l;
        double xv = (double)xrow[d];
        const float4* wr = (const float4*)(Wr + d * NE);
        float4 w0 = wr[0], w1 = wr[1], w2 = wr[2], w3 = wr[3];
        z[0]  += xv * w0.x; z[1]  += xv * w0.y; z[2]  += xv * w0.z; z[3]  += xv * w0.w;
        z[4]  += xv * w1.x; z[5]  += xv * w1.y; z[6]  += xv * w1.z; z[7]  += xv * w1.w;
        z[8]  += xv * w2.x; z[9]  += xv * w2.y; z[10] += xv * w2.z; z[11] += xv * w2.w;
        z[12] += xv * w3.x; z[13] += xv * w3.y; z[14] += xv * w3.z; z[15] += xv * w3.w;
    }
    // fused cast: two 8-elem chunks per lane (row is L1-hot)
    const float4* xv4 = (const float4*)xrow;
#pragma unroll
    for (int h2 = 0; h2 < 2; h2++) {
        int base = h2 * 512 + l * 8;
        float4 a = xv4[h2 * 128 + l * 2];
        float4 b = xv4[h2 * 128 + l * 2 + 1];
        union { unsigned short u[8]; uint4 v; } p;
        p.u[0] = __builtin_bit_cast(unsigned short, (_Float16)a.x);
        p.u[1] = __builtin_bit_cast(unsigned short, (_Float16)a.y);
        p.u[2] = __builtin_bit_cast(unsigned short, (_Float16)a.z);
        p.u[3] = __builtin_bit_cast(unsigned short, (_Float16)a.w);
        p.u[4] = __builtin_bit_cast(unsigned short, (_Float16)b.x);
        p.u[5] = __builtin_bit_cast(unsigned short, (_Float16)b.y);
        p.u[6] = __builtin_bit_cast(unsigned short, (_Float16)b.z);
        p.u[7] = __builtin_bit_cast(unsigned short, (_Float16)b.w);
        *(uint4*)(xb + (size_t)t * DIM + base) = p.v;
    }
#pragma unroll
    for (int e = 0; e < NE; e++) {
#pragma unroll
        for (int m = 1; m < 64; m <<= 1) z[e] += __shfl_xor(z[e], m, 64);
    }
    if (l == 0) {
        bool taken[NE];
#pragma unroll
        for (int e = 0; e < NE; e++) taken[e] = false;
        int idx[TOPK]; double sel[TOPK];
        for (int k = 0; k < TOPK; k++) {
            int bi = 0; double bv = -1.0e300;
            for (int e = 0; e < NE; e++)
                if (!taken[e] && z[e] > bv) { bv = z[e]; bi = e; }
            taken[bi] = true; idx[k] = bi; sel[k] = bv;
        }
        double m = sel[0];
        double ex[TOPK]; double s = 0.0;
        for (int k = 0; k < TOPK; k++) { ex[k] = exp(sel[k] - m); s += ex[k]; }
        for (int k = 0; k < TOPK; k++) {
            tokIdx[t * TOPK + k] = idx[k];
            tokW[t * TOPK + k]   = (float)(ex[k] / s);
        }
    }
}

// ------------------------------------------------------------------ binning --
// 16 blocks, one per expert (16x the parallelism of the single-block version).
// ballot rank within wave + LDS cross-wave prefix; deterministic order.
__global__ __launch_bounds__(256) void bin_kernel(
    const int* __restrict__ tokIdx,
    int* __restrict__ cnt, int* __restrict__ bpair)
{
    int e = blockIdx.x;
    int tid = threadIdx.x, lane = tid & 63, wv = tid >> 6;
    __shared__ int wsum[4];
    __shared__ int sbase;
    if (tid == 0) sbase = 0;
    __syncthreads();
    unsigned long long lt = (1ULL << lane) - 1ULL;
#pragma unroll 1
    for (int c0 = 0; c0 < NPAIR; c0 += 1024) {
        int i0 = c0 + tid * 4;
        int4 v = *(const int4*)(tokIdx + i0);
        int m[4] = {v.x == e, v.y == e, v.z == e, v.w == e};
        int r[4]; int wcnt = 0;
#pragma unroll
        for (int j = 0; j < 4; j++) {
            unsigned long long bal = __ballot(m[j] != 0);
            r[j] = wcnt + __popcll(bal & lt);
            wcnt += __popcll(bal);
        }
        if (lane == 0) wsum[wv] = wcnt;
        __syncthreads();
        int woff = sbase;
        for (int k = 0; k < wv; k++) woff += wsum[k];
#pragma unroll
        for (int j = 0; j < 4; j++)
            if (m[j]) bpair[e * CAP + woff + r[j]] = i0 + j;
        __syncthreads();
        if (tid == 0) sbase += wsum[0] + wsum[1] + wsum[2] + wsum[3];
        __syncthreads();
    }
    if (tid == 0) cnt[e] = sbase;
}

// ----------------------------------------------------------- weight prep ----
// one launch for Wg+Wu+Wd: [E][R][C] f32 -> B^T tiled f16 images
// out[e][cb][kt][RI][32]; z = which*16 + e.
__global__ __launch_bounds__(256) void prep_weight_kernel(
    const float* __restrict__ Wg, const float* __restrict__ Wu,
    const float* __restrict__ Wd,
    unsigned short* __restrict__ Wg_t, unsigned short* __restrict__ Wu_t,
    unsigned short* __restrict__ Wd_t)
{
    int z = blockIdx.y;
    int which = z >> 4, e = z & 15;
    const float* src; unsigned short* dst; int R, C, RIL;
    if (which == 0)      { src = Wg; dst = Wg_t; R = DIM; C = NF;  RIL = 6; }
    else if (which == 1) { src = Wu; dst = Wu_t; R = DIM; C = NF;  RIL = 6; }
    else                 { src = Wd; dst = Wd_t; R = NF;  C = DIM; RIL = 7; }
    int bx = blockIdx.x;
    int cbl, rbl;
    if (which < 2) { cbl = bx & 7;  rbl = bx >> 3; }
    else           { cbl = bx & 15; rbl = bx >> 4; }
    int c0 = cbl * 64, r0 = rbl * 64;

    __shared__ float tile[64][65];
    const float* s = src + (size_t)e * R * C;
    int t = threadIdx.x;
    int tr = t >> 4, tc = (t & 15) * 4;
#pragma unroll
    for (int i = 0; i < 4; i++) {
        int row = i * 16 + tr;
        float4 v = *(const float4*)(s + (size_t)(r0 + row) * C + c0 + tc);
        tile[row][tc + 0] = v.x; tile[row][tc + 1] = v.y;
        tile[row][tc + 2] = v.z; tile[row][tc + 3] = v.w;
    }
    __syncthreads();
    int ktPerE = R >> 5;
    int cbPerE = C >> RIL;
    int imgSz  = (1 << RIL) * 32;
#pragma unroll
    for (int i = 0; i < 4; i++) {
        int nr = i * 16 + tr;
        int orow = c0 + nr;
        int k0 = r0 + tc;
        int cb = orow >> RIL;
        int r  = orow & ((1 << RIL) - 1);
        int kt = k0 >> 5;
        size_t off = ((size_t)(e * cbPerE + cb) * ktPerE + kt) * imgSz
                   + r * 32 + (k0 & 31);
        union { unsigned short u[4]; uint2 v; } p;
#pragma unroll
        for (int j = 0; j < 4; j++)
            p.u[j] = __builtin_bit_cast(unsigned short, (_Float16)tile[tc + j][nr]);
        *(uint2*)(dst + off) = p.v;
    }
}

// LDS chunk swizzle (R5-proven: 0 measured conflicts)
__device__ __forceinline__ int ldsw(int row, int chunk) {
    return row * 32 + (chunk ^ ((row >> 1) & 3)) * 8;
}

// per-block tile lookup from cnt[] (replaces tileE/tileMt/ptile arrays)
__device__ __forceinline__ bool find_tile(const int* __restrict__ cnt,
                                          int ti, int& e, int& mt, int& tbase) {
    int rt = 0;
#pragma unroll 1
    for (int ee = 0; ee < NE; ee++) {
        int nt = (cnt[ee] + 127) >> 7;
        if (ti < rt + nt) { e = ee; mt = ti - rt; tbase = rt; return true; }
        rt += nt;
    }
    return false;
}

// --------------------------------------------------------- gate/up + silu ----
// R5-proven structure: 128 slots x 64 f-cols, BK=32, register staging.
__global__ __launch_bounds__(256) void ffn_gate_up_kernel(
    const unsigned short* __restrict__ xb,
    const unsigned short* __restrict__ Wg_t,   // [e][fb8][kt32][64][32]
    const unsigned short* __restrict__ Wu_t,
    const int* __restrict__ cnt,
    const int* __restrict__ bpair,
    unsigned short* __restrict__ h_t)          // [tile][kt16][128][32]
{
    int fb = blockIdx.x, ti = blockIdx.y;
    int e, mt, tbase;
    if (!find_tile(cnt, ti, e, mt, tbase)) return;
    int count = cnt[e];

    __shared__ __align__(16) unsigned short sX[128 * 32];
    __shared__ __align__(16) unsigned short sG[64 * 32];
    __shared__ __align__(16) unsigned short sU[64 * 32];
    __shared__ int sTok[128];

    int tid = threadIdx.x, lane = tid & 63, w = tid >> 6;
    if (tid < 128) {
        int pos = mt * 128 + tid;
        sTok[tid] = bpair[e * CAP + min(pos, count - 1)] >> 2;
    }
    __syncthreads();

    int xr0 = tid >> 2, xc = tid & 3;
    int xr1 = xr0 + 64;
    const unsigned short* gx0 = xb + (size_t)sTok[xr0] * DIM + xc * 8;
    const unsigned short* gx1 = xb + (size_t)sTok[xr1] * DIM + xc * 8;
    const unsigned short* gsrc = Wg_t + ((size_t)(e * 8 + fb) * 32) * 2048 + tid * 8;
    const unsigned short* usrc = Wu_t + ((size_t)(e * 8 + fb) * 32) * 2048 + tid * 8;

    unsigned short* wx0 = &sX[ldsw(xr0, xc)];
    unsigned short* wx1 = &sX[ldsw(xr1, xc)];
    unsigned short* wg  = &sG[ldsw(xr0, xc)];
    unsigned short* wu  = &sU[ldsw(xr0, xc)];

    int row = lane & 15, q = lane >> 4;
    int rw = w & 1, cw = w >> 1;
    int aoff[4], goff[2];
#pragma unroll
    for (int mi = 0; mi < 4; mi++) aoff[mi] = ldsw(rw * 64 + mi * 16 + row, q);
#pragma unroll
    for (int ni = 0; ni < 2; ni++) goff[ni] = ldsw(cw * 32 + ni * 16 + row, q);

    v4f accG[4][2], accU[4][2];
    v4f zero = {0.f, 0.f, 0.f, 0.f};
#pragma unroll
    for (int mi = 0; mi < 4; mi++)
#pragma unroll
        for (int ni = 0; ni < 2; ni++) { accG[mi][ni] = zero; accU[mi][ni] = zero; }

    uint4 rx0 = *(const uint4*)(gx0);
    uint4 rx1 = *(const uint4*)(gx1);
    uint4 rg  = *(const uint4*)(gsrc);
    uint4 ru  = *(const uint4*)(usrc);

#pragma unroll 1
    for (int kt = 0; kt < 32; kt++) {
        __syncthreads();
        *(uint4*)wx0 = rx0;
        *(uint4*)wx1 = rx1;
        *(uint4*)wg  = rg;
        *(uint4*)wu  = ru;
        if (kt < 31) {
            rx0 = *(const uint4*)(gx0 + (kt + 1) * 32);
            rx1 = *(const uint4*)(gx1 + (kt + 1) * 32);
            rg  = *(const uint4*)(gsrc + (size_t)(kt + 1) * 2048);
            ru  = *(const uint4*)(usrc + (size_t)(kt + 1) * 2048);
        }
        __syncthreads();
        v8h a[4], bg[2], bu[2];
#pragma unroll
        for (int mi = 0; mi < 4; mi++) a[mi] = *(const v8h*)&sX[aoff[mi]];
#pragma unroll
        for (int ni = 0; ni < 2; ni++) {
            bg[ni] = *(const v8h*)&sG[goff[ni]];
            bu[ni] = *(const v8h*)&sU[goff[ni]];
        }
#pragma unroll
        for (int mi = 0; mi < 4; mi++)
#pragma unroll
            for (int ni = 0; ni < 2; ni++) {
                accG[mi][ni] = __builtin_amdgcn_mfma_f32_16x16x32_f16(a[mi], bg[ni], accG[mi][ni], 0, 0, 0);
                accU[mi][ni] = __builtin_amdgcn_mfma_f32_16x16x32_f16(a[mi], bu[ni], accU[mi][ni], 0, 0, 0);
            }
    }

    size_t himg = (size_t)(tbase + mt) * 16;
#pragma unroll
    for (int mi = 0; mi < 4; mi++)
#pragma unroll
        for (int ni = 0; ni < 2; ni++) {
            int f = fb * 64 + cw * 32 + ni * 16 + row;    // C/D: col = lane&15
#pragma unroll
            for (int i = 0; i < 4; i++) {
                int rl = rw * 64 + mi * 16 + q * 4 + i;   // C/D: row = quad*4+reg
                int pos = mt * 128 + rl;
                if (pos < count) {
                    float gv = accG[mi][ni][i];
                    float uv = accU[mi][ni][i];
                    float hv = gv * uv / (1.0f + __expf(-gv));
                    size_t off = (himg + (f >> 5)) * 4096 + rl * 32 + (f & 31);
                    h_t[off] = __builtin_bit_cast(unsigned short, (_Float16)hv);
                }
            }
        }
}

// ----------------------------------------------------------- down (no atomics)
__global__ __launch_bounds__(256) void ffn_down_kernel(
    const unsigned short* __restrict__ h_t,
    const unsigned short* __restrict__ Wd_t,   // [e][db8][kt16][128][32]
    const int* __restrict__ cnt,
    const int* __restrict__ bpair,
    unsigned short* __restrict__ part)         // [NPAIR][DIM] f16
{
    int ti = blockIdx.x, db = blockIdx.y;
    int e, mt, tbase;
    if (!find_tile(cnt, ti, e, mt, tbase)) return;
    int count = cnt[e];

    __shared__ __align__(16) unsigned short sH[128 * 32];
    __shared__ __align__(16) unsigned short sW[128 * 32];
    __shared__ int sPair[128];

    int tid = threadIdx.x, lane = tid & 63, w = tid >> 6;
    if (tid < 128) {
        int pos = mt * 128 + tid;
        sPair[tid] = bpair[e * CAP + min(pos, count - 1)];
    }
    __syncthreads();

    int r0 = tid >> 2, c = tid & 3;
    int r1 = r0 + 64;
    const unsigned short* hsrc = h_t + ((size_t)(tbase + mt) * 16) * 4096 + tid * 8;
    const unsigned short* wsrc = Wd_t + ((size_t)(e * 8 + db) * 16) * 4096 + tid * 8;

    unsigned short* wh0 = &sH[ldsw(r0, c)];
    unsigned short* wh1 = &sH[ldsw(r1, c)];
    unsigned short* ww0 = &sW[ldsw(r0, c)];
    unsigned short* ww1 = &sW[ldsw(r1, c)];

    int row = lane & 15, q = lane >> 4;
    int rw = w & 1, cw = w >> 1;
    int aoff[4], boff[4];
#pragma unroll
    for (int mi = 0; mi < 4; mi++) aoff[mi] = ldsw(rw * 64 + mi * 16 + row, q);
#pragma unroll
    for (int ni = 0; ni < 4; ni++) boff[ni] = ldsw(cw * 64 + ni * 16 + row, q);

    v4f acc[4][4];
    v4f zero = {0.f, 0.f, 0.f, 0.f};
#pragma unroll
    for (int mi = 0; mi < 4; mi++)
#pragma unroll
        for (int ni = 0; ni < 4; ni++) acc[mi][ni] = zero;

    uint4 rh0 = *(const uint4*)(hsrc);
    uint4 rh1 = *(const uint4*)(hsrc + 2048);
    uint4 rw0 = *(const uint4*)(wsrc);
    uint4 rw1 = *(const uint4*)(wsrc + 2048);

#pragma unroll 1
    for (int kt = 0; kt < 16; kt++) {
        __syncthreads();
        *(uint4*)wh0 = rh0;
        *(uint4*)wh1 = rh1;
        *(uint4*)ww0 = rw0;
        *(uint4*)ww1 = rw1;
        if (kt < 15) {
            rh0 = *(const uint4*)(hsrc + (size_t)(kt + 1) * 4096);
            rh1 = *(const uint4*)(hsrc + (size_t)(kt + 1) * 4096 + 2048);
            rw0 = *(const uint4*)(wsrc + (size_t)(kt + 1) * 4096);
            rw1 = *(const uint4*)(wsrc + (size_t)(kt + 1) * 4096 + 2048);
        }
        __syncthreads();
        v8h a[4], b[4];
#pragma unroll
        for (int mi = 0; mi < 4; mi++) a[mi] = *(const v8h*)&sH[aoff[mi]];
#pragma unroll
        for (int ni = 0; ni < 4; ni++) b[ni] = *(const v8h*)&sW[boff[ni]];
#pragma unroll
        for (int mi = 0; mi < 4; mi++)
#pragma unroll
            for (int ni = 0; ni < 4; ni++)
                acc[mi][ni] = __builtin_amdgcn_mfma_f32_16x16x32_f16(a[mi], b[ni], acc[mi][ni], 0, 0, 0);
    }

#pragma unroll
    for (int mi = 0; mi < 4; mi++)
#pragma unroll
        for (int ni = 0; ni < 4; ni++) {
            int col = db * 128 + cw * 64 + ni * 16 + row;
#pragma unroll
            for (int i = 0; i < 4; i++) {
                int rl = rw * 64 + mi * 16 + q * 4 + i;
                int pos = mt * 128 + rl;
                if (pos < count) {
                    int p = sPair[rl];
                    part[(size_t)p * DIM + col] =
                        __builtin_bit_cast(unsigned short, (_Float16)acc[mi][ni][i]);
                }
            }
        }
}

// ---------------------------------------------------------------- combine ----
__global__ __launch_bounds__(256) void combine_kernel(
    const unsigned short* __restrict__ part, const float* __restrict__ tokW,
    float* __restrict__ out)
{
    int gid = blockIdx.x * 256 + threadIdx.x;
    int t = gid >> 8;
    int c = (gid & 255) * 4;
    float4 r = {0.f, 0.f, 0.f, 0.f};
#pragma unroll
    for (int k = 0; k < TOPK; k++) {
        float wk = tokW[t * TOPK + k];
        union { uint2 u; _Float16 h[4]; } cv;
        cv.u = *(const uint2*)(part + ((size_t)(t * TOPK + k)) * DIM + c);
        r.x += wk * (float)cv.h[0];
        r.y += wk * (float)cv.h[1];
        r.z += wk * (float)cv.h[2];
        r.w += wk * (float)cv.h[3];
    }
    *(float4*)(out + (size_t)t * DIM + c) = r;
}

// ------------------------------------------------------------------- host ----
extern "C" void kernel_launch(void* const* d_in, const int* in_sizes, int n_in,
                              void* d_out, int out_size, void* d_ws, size_t ws_size,
                              hipStream_t stream)
{
    const float* x  = (const float*)d_in[0];
    const float* Wr = (const float*)d_in[1];
    const float* Wg = (const float*)d_in[2];
    const float* Wu = (const float*)d_in[3];
    const float* Wd = (const float*)d_in[4];
    float* out = (float*)d_out;
    char* ws = (char*)d_ws;

    size_t off = 0;
    int* tokIdx = (int*)(ws + off);   off += (size_t)NPAIR * 4;
    float* tokW = (float*)(ws + off); off += (size_t)NPAIR * 4;
    int* cnt    = (int*)(ws + off);   off += 256;
    int* bpair  = (int*)(ws + off);   off += (size_t)NE * CAP * 4;
    unsigned short* xb   = (unsigned short*)(ws + off); off += (size_t)N_TOK * DIM * 2;
    unsigned short* Wg_t = (unsigned short*)(ws + off); off += (size_t)NE * DIM * NF * 2;
    unsigned short* Wu_t = (unsigned short*)(ws + off); off += (size_t)NE * DIM * NF * 2;
    unsigned short* Wd_t = (unsigned short*)(ws + off); off += (size_t)NE * DIM * NF * 2;
    unsigned short* h_t  = (unsigned short*)(ws + off); off += (size_t)MAXTILES * 16 * 4096 * 2;
    unsigned short* part = (unsigned short*)(ws + off); off += (size_t)NPAIR * DIM * 2;

    router_kernel<<<N_TOK, 64, 0, stream>>>(x, Wr, tokIdx, tokW, xb);
    bin_kernel<<<NE, 256, 0, stream>>>(tokIdx, cnt, bpair);
    prep_weight_kernel<<<dim3(128, 48), 256, 0, stream>>>(Wg, Wu, Wd, Wg_t, Wu_t, Wd_t);
    ffn_gate_up_kernel<<<dim3(8, MAXTILES), 256, 0, stream>>>(
        xb, Wg_t, Wu_t, cnt, bpair, h_t);
    ffn_down_kernel<<<dim3(MAXTILES, 8), 256, 0, stream>>>(
        h_t, Wd_t, cnt, bpair, part);
    combine_kernel<<<(N_TOK * DIM) / (256 * 4), 256, 0, stream>>>(part, tokW, out);
}